// Round 7
// baseline (1532.722 us; speedup 1.0000x reference)
//
#include <hip/hip_runtime.h>

// FHN stacked-LSTM, B=64, H=512, T=1000. v7: XCD-local cohorts.
//  - 8 cohorts (8 batches each), one per XCD: blocks claim slots in
//    roster[XCC_ID]; first 64 claimants on an XCD form its cohort. All
//    cohort traffic then stays in that XCD's private L2.
//  - Exchange: tagged 8B packets {epoch<<1|stab, f32}. Writers DUAL-PUBLISH:
//    plain store (write-through L1 -> local L2) + agent atomic store (L3).
//    Readers: inline-asm sc0 loads (L1-bypass, L2-hit) with per-packet tag
//    verification; any stale packet falls back to agent loads of the L3 copy.
//    Correct under ANY sc0 semantics; fast when sc0 = L2 scope.
//  - epsilon-stability exit (|dh|<1e-6, RSTAB=10) -> fill + return (as v5/v6).
//  - ws_size guard: if scratch < ~1.03MB, launch the proven v6 kernel.

#define B_ 64
#define H_ 512
#define T_ 1000
#define NTHR 256
#define RSTAB 10
#define EPS_STAB 1e-6f

typedef unsigned long long ull;
typedef unsigned int uint4v __attribute__((ext_vector_type(4)));

__device__ __forceinline__ float sigf(float x) { return 1.0f / (1.0f + expf(-x)); }

#define CH8(p, w0v, w1v, h0v, h1v) \
    p = fmaf((w0v).x, (h0v).x, fmaf((w0v).y, (h0v).y, fmaf((w0v).z, (h0v).z, fmaf((w0v).w, (h0v).w, \
        fmaf((w1v).x, (h1v).x, fmaf((w1v).y, (h1v).y, fmaf((w1v).z, (h1v).z, fmaf((w1v).w, (h1v).w, p))))))))

// ======================= v7: XCD-local kernel =======================
#define NCOH 8
#define CB 8                 // batches per cohort
#define NW 64                // worker blocks per cohort
#define FAST_TRIES 1024
#define W7_ROST 0
#define W7_A    4096                           // plain/L2 buffers: [coh][ph][4096 pkt]
#define W7_B    (4096 + NCOH * 2 * 4096 * 8)   // agent/L3 copies, same layout
#define W7_NEED (W7_B + NCOH * 2 * 4096 * 8)   // 1052672 B

__device__ __forceinline__ ull ld8_sc0(const ull* p) {
    ull r;
    asm volatile("global_load_dwordx2 %0, %1, off sc0\n\ts_waitcnt vmcnt(0)"
                 : "=v"(r) : "v"(p) : "memory");
    return r;
}

__device__ __forceinline__ void publish(ull* fastW, ull* slowW, int u,
                                        unsigned ep, unsigned sb, float v)
{
    ull pkt = ((ull)((ep << 1) | sb) << 32) | (ull)__float_as_uint(v);
    ((volatile ull*)fastW)[u] = pkt;                                   // -> local L2
    __hip_atomic_store(&slowW[u], pkt, __ATOMIC_RELAXED, __HIP_MEMORY_SCOPE_AGENT); // -> L3
}

// Read 4096 tagged packets -> staged[b][512]. Fast: one asm burst of 8
// dwordx4 sc0 loads/thread, verify tags, bounded sc0 retries; fall back to
// agent loads of the L3 copy per packet. Returns AND of stab bits seen.
__device__ __forceinline__ unsigned read_cohort(const ull* fastB, const ull* slowB,
                                                unsigned ep, float (*st)[516],
                                                int tid, int* slowMode)
{
    uint4v r0 = {0,0,0,0}, r1 = {0,0,0,0}, r2 = {0,0,0,0}, r3 = {0,0,0,0};
    uint4v r4 = {0,0,0,0}, r5 = {0,0,0,0}, r6 = {0,0,0,0}, r7 = {0,0,0,0};
    const ull* p0 = fastB + (0 * 512 + tid * 2);
    const ull* p1 = fastB + (1 * 512 + tid * 2);
    const ull* p2 = fastB + (2 * 512 + tid * 2);
    const ull* p3 = fastB + (3 * 512 + tid * 2);
    const ull* p4 = fastB + (4 * 512 + tid * 2);
    const ull* p5 = fastB + (5 * 512 + tid * 2);
    const ull* p6 = fastB + (6 * 512 + tid * 2);
    const ull* p7 = fastB + (7 * 512 + tid * 2);
    if (!*slowMode) {
        asm volatile(
            "global_load_dwordx4 %0, %8, off sc0\n\t"
            "global_load_dwordx4 %1, %9, off sc0\n\t"
            "global_load_dwordx4 %2, %10, off sc0\n\t"
            "global_load_dwordx4 %3, %11, off sc0\n\t"
            "global_load_dwordx4 %4, %12, off sc0\n\t"
            "global_load_dwordx4 %5, %13, off sc0\n\t"
            "global_load_dwordx4 %6, %14, off sc0\n\t"
            "global_load_dwordx4 %7, %15, off sc0\n\t"
            "s_waitcnt vmcnt(0)"
            : "=&v"(r0), "=&v"(r1), "=&v"(r2), "=&v"(r3),
              "=&v"(r4), "=&v"(r5), "=&v"(r6), "=&v"(r7)
            : "v"(p0), "v"(p1), "v"(p2), "v"(p3),
              "v"(p4), "v"(p5), "v"(p6), "v"(p7)
            : "memory");
        __builtin_amdgcn_sched_barrier(0);
    }
    unsigned stab = 1u;
#define HANDLE(q, RQ, e) { \
    unsigned tg = (e) ? (RQ).w : (RQ).y; \
    unsigned vl = (e) ? (RQ).z : (RQ).x; \
    const int p = (q) * 512 + tid * 2 + (e); \
    if (!*slowMode) { \
        int it = 0; \
        while ((tg >> 1) != ep) { \
            if (++it > FAST_TRIES) { *slowMode = 1; break; } \
            ull pk = ld8_sc0(fastB + p); tg = (unsigned)(pk >> 32); vl = (unsigned)pk; \
        } \
    } \
    if (*slowMode && (tg >> 1) != ep) { \
        int sp = 0; ull pk; \
        do { pk = __hip_atomic_load(slowB + p, __ATOMIC_RELAXED, __HIP_MEMORY_SCOPE_AGENT); } \
        while ((((unsigned)(pk >> 32)) >> 1) != ep && ++sp < 4000000); \
        tg = (unsigned)(pk >> 32); vl = (unsigned)pk; \
    } \
    stab &= tg & 1u; \
    { const int j = p & 63; st[j >> 3][((p >> 6) << 3) + (j & 7)] = __uint_as_float(vl); } }
    HANDLE(0, r0, 0) HANDLE(0, r0, 1)
    HANDLE(1, r1, 0) HANDLE(1, r1, 1)
    HANDLE(2, r2, 0) HANDLE(2, r2, 1)
    HANDLE(3, r3, 0) HANDLE(3, r3, 1)
    HANDLE(4, r4, 0) HANDLE(4, r4, 1)
    HANDLE(5, r5, 0) HANDLE(5, r5, 1)
    HANDLE(6, r6, 0) HANDLE(6, r6, 1)
    HANDLE(7, r7, 0) HANDLE(7, r7, 1)
#undef HANDLE
    return stab;
}

__device__ __forceinline__ void compute_gates8(const float4 (&wr)[3][4], const float (*st)[516],
                                               int ks, float (&acc)[3][8])
{
    #pragma unroll
    for (int g = 0; g < 3; ++g)
        #pragma unroll
        for (int b = 0; b < 8; ++b) acc[g][b] = 0.f;
    #pragma unroll
    for (int j = 0; j < 4; ++j) {
        const int kw = 4 * (ks + 32 * j);
        #pragma unroll
        for (int b = 0; b < 8; ++b) {
            const float4 h4 = *(const float4*)&st[b][kw];
            #pragma unroll
            for (int g = 0; g < 3; ++g)
                acc[g][b] = fmaf(wr[g][j].x, h4.x, fmaf(wr[g][j].y, h4.y,
                            fmaf(wr[g][j].z, h4.z, fmaf(wr[g][j].w, h4.w, acc[g][b]))));
        }
    }
}

__device__ __forceinline__ void reduce_write8(float (&acc)[3][8], float (*red)[8][25],
                                              int lane, int wv)
{
    #pragma unroll
    for (int g = 0; g < 3; ++g)
        #pragma unroll
        for (int b = 0; b < 8; ++b) {
            float v = acc[g][b];
            v += __shfl_xor(v, 8);
            v += __shfl_xor(v, 16);
            v += __shfl_xor(v, 32);
            acc[g][b] = v;
        }
    if ((lane & 56) == 0) {
        const int nn = lane & 7;
        #pragma unroll
        for (int g = 0; g < 3; ++g)
            #pragma unroll
            for (int b = 0; b < 8; ++b)
                red[wv][nn][g * 8 + b] = acc[g][b];
    }
    __syncthreads();
}

__global__ __launch_bounds__(NTHR, 2)
void fhn_v7(const float* __restrict__ u0, const float* __restrict__ w0,
            const float* __restrict__ Kp,
            const float* __restrict__ W_in, const float* __restrict__ b_in,
            const float* __restrict__ W0, const float* __restrict__ bi0, const float* __restrict__ bh0,
            const float* __restrict__ W1, const float* __restrict__ bi1, const float* __restrict__ bh1,
            const float* __restrict__ Wu, const float* __restrict__ bu,
            const float* __restrict__ Ww, const float* __restrict__ bw,
            float* __restrict__ out, unsigned char* __restrict__ wsb)
{
    __shared__ float staged[CB][516];
    __shared__ float red[4][8][25];
    __shared__ float wu_s[H_], ww_s[H_];
    __shared__ float bias_s[48];
    __shared__ int s_slot;
    __shared__ int s_w4[4];

    const int tid = threadIdx.x;
    if (tid == 0) {
        unsigned xcc;
        asm volatile("s_getreg_b32 %0, hwreg(HW_REG_XCC_ID)" : "=s"(xcc));
        xcc &= 7u;
        unsigned* roster = (unsigned*)(wsb + W7_ROST);
        unsigned slot = __hip_atomic_fetch_add(&roster[xcc], 1u,
                                               __ATOMIC_RELAXED, __HIP_MEMORY_SCOPE_AGENT);
        s_slot = (slot < NW) ? (int)(xcc * NW + slot) : -1;
    }
    __syncthreads();
    const int sl = s_slot;
    if (sl < 0) return;                       // non-worker
    const int coh = sl >> 6, ng = sl & 63;    // cohort = XCD, neuron group
    const int B0 = coh * CB;
    const int n = tid & 7, ks = tid >> 3;
    const int lane = tid & 63, wv = tid >> 6;

    ull* fastM = (ull*)(wsb + W7_A) + (size_t)(coh * 2 + 0) * 4096;
    ull* fastH = (ull*)(wsb + W7_A) + (size_t)(coh * 2 + 1) * 4096;
    ull* slowM = (ull*)(wsb + W7_B) + (size_t)(coh * 2 + 0) * 4096;
    ull* slowH = (ull*)(wsb + W7_B) + (size_t)(coh * 2 + 1) * 4096;

    // ---------------- prologue: weights (live gates i,g,o) -> registers
    float4 w0r[3][4], w1r[3][4];
    {
        const int gmap[3] = {0, 2, 3};
        #pragma unroll
        for (int g = 0; g < 3; ++g) {
            const float* r0 = W0 + (size_t)(gmap[g] * H_ + ng * 8 + n) * H_;
            const float* r1 = W1 + (size_t)(gmap[g] * H_ + ng * 8 + n) * H_;
            #pragma unroll
            for (int j = 0; j < 4; ++j) {
                w0r[g][j] = *(const float4*)(r0 + 4 * (ks + 32 * j));
                w1r[g][j] = *(const float4*)(r1 + 4 * (ks + 32 * j));
            }
        }
    }
    for (int i = tid; i < H_; i += NTHR) { wu_s[i] = Wu[i]; ww_s[i] = Ww[i]; }
    if (tid < 48) {
        const int gmap[3] = {0, 2, 3};
        int L = tid / 24, r = tid % 24, g = r >> 3, nn = r & 7;
        int row = gmap[g] * H_ + ng * 8 + nn;
        bias_s[tid] = L ? (bi1[row] + bh1[row]) : (bi0[row] + bh0[row]);
    }
    const float buv = bu[0], bwv = bw[0];

    // step 0 input: x = [u0,w0,K] @ W_in.T + b_in for our 8 batches
    for (int i = tid; i < CB * H_; i += NTHR) {
        int b = i >> 9, k = i & 511;
        staged[b][k] = u0[B0 + b] * W_in[k * 3] + w0[B0 + b] * W_in[k * 3 + 1]
                     + Kp[B0 + b] * W_in[k * 3 + 2] + b_in[k];
    }
    __syncthreads();

    int slowMode = 0;
    float hprev = 0.f;
    int run = 0;
    float acc[3][8];

    for (int t = 0; t < T_; ++t) {
        // ---------------- phase A: consume h(t-1), produce m(t)
        if (t > 0) {
            unsigned stv = read_cohort(fastH, slowH, (unsigned)(2 * t), staged, tid, &slowMode);
            int av = __all((int)stv);
            if (lane == 0) s_w4[wv] = av;
            __syncthreads();                  // staged complete + stab gathered
            int stabAll = s_w4[0] & s_w4[1] & s_w4[2] & s_w4[3];
            run = stabAll ? run + 1 : 0;
            if (run >= RSTAB) {
                if (ng < CB && wv < 2) {      // batch bb=ng; wave0=u, wave1=w
                    const float4* h4p = (const float4*)&staged[ng][lane << 3];
                    const float4 h0v = h4p[0], h1v = h4p[1];
                    const float* vec = wv ? &ww_s[lane << 3] : &wu_s[lane << 3];
                    const float4 va = ((const float4*)vec)[0], vb = ((const float4*)vec)[1];
                    float p = 0.f;
                    CH8(p, va, vb, h0v, h1v);
                    #pragma unroll
                    for (int off = 1; off < 64; off <<= 1) p += __shfl_xor(p, off);
                    p += wv ? bwv : buv;      // uniform across the wave
                    const int tau = t - 1;
                    const size_t base = (wv ? (size_t)B_ * T_ : 0) + (size_t)(B0 + ng) * T_;
                    for (int tp = tau + lane; tp < T_; tp += 64) out[base + tp] = p;
                }
                return;
            }
        }

        compute_gates8(w0r, staged, ks, acc);
        reduce_write8(acc, red, lane, wv);
        if (tid < 64) {
            const int b = tid >> 3, nn = tid & 7;
            float si = red[0][nn][b]      + red[1][nn][b]      + red[2][nn][b]      + red[3][nn][b]      + bias_s[nn];
            float sg = red[0][nn][8 + b]  + red[1][nn][8 + b]  + red[2][nn][8 + b]  + red[3][nn][8 + b]  + bias_s[8 + nn];
            float so = red[0][nn][16 + b] + red[1][nn][16 + b] + red[2][nn][16 + b] + red[3][nn][16 + b] + bias_s[16 + nn];
            float c = sigf(si) * tanhf(sg);
            float m = sigf(so) * tanhf(c);
            publish(fastM, slowM, ng * 64 + tid, (unsigned)(2 * t + 1), 1u, m);
        }
        // u/w outputs for step t-1 (staged still h(t-1)), off critical path
        if (t > 0 && ng < CB && wv < 2) {
            const float4* h4p = (const float4*)&staged[ng][lane << 3];
            const float4 h0v = h4p[0], h1v = h4p[1];
            const float* vec = wv ? &ww_s[lane << 3] : &wu_s[lane << 3];
            const float4 va = ((const float4*)vec)[0], vb = ((const float4*)vec)[1];
            float p = 0.f;
            CH8(p, va, vb, h0v, h1v);
            #pragma unroll
            for (int off = 1; off < 64; off <<= 1) p += __shfl_xor(p, off);
            if (lane == 0)
                out[(wv ? (size_t)B_ * T_ : 0) + (size_t)(B0 + ng) * T_ + (t - 1)] = p + (wv ? bwv : buv);
        }
        __syncthreads();                      // staged free before overwrite

        // ---------------- phase B: consume m(t), produce h(t) + stability
        read_cohort(fastM, slowM, (unsigned)(2 * t + 1), staged, tid, &slowMode);
        __syncthreads();
        compute_gates8(w1r, staged, ks, acc);
        reduce_write8(acc, red, lane, wv);
        if (tid < 64) {
            const int b = tid >> 3, nn = tid & 7;
            float si = red[0][nn][b]      + red[1][nn][b]      + red[2][nn][b]      + red[3][nn][b]      + bias_s[24 + nn];
            float sg = red[0][nn][8 + b]  + red[1][nn][8 + b]  + red[2][nn][8 + b]  + red[3][nn][8 + b]  + bias_s[32 + nn];
            float so = red[0][nn][16 + b] + red[1][nn][16 + b] + red[2][nn][16 + b] + red[3][nn][16 + b] + bias_s[40 + nn];
            float c = sigf(si) * tanhf(sg);
            float h = sigf(so) * tanhf(c);
            int myst = (fabsf(h - hprev) < EPS_STAB) ? 1 : 0;
            hprev = h;
            unsigned sb = (t == 0) ? 0u : (unsigned)__all(myst);   // tid<64 == wave 0
            publish(fastH, slowH, ng * 64 + tid, (unsigned)(2 * t + 2), sb, h);
        }
    }
    // ---------------- epilogue (no exit): outputs for t = T-1
    if (ng < CB) {
        read_cohort(fastH, slowH, (unsigned)(2 * T_), staged, tid, &slowMode);
        __syncthreads();
        if (wv < 2) {
            const float4* h4p = (const float4*)&staged[ng][lane << 3];
            const float4 h0v = h4p[0], h1v = h4p[1];
            const float* vec = wv ? &ww_s[lane << 3] : &wu_s[lane << 3];
            const float4 va = ((const float4*)vec)[0], vb = ((const float4*)vec)[1];
            float p = 0.f;
            CH8(p, va, vb, h0v, h1v);
            #pragma unroll
            for (int off = 1; off < 64; off <<= 1) p += __shfl_xor(p, off);
            if (lane == 0)
                out[(wv ? (size_t)B_ * T_ : 0) + (size_t)(B0 + ng) * T_ + (T_ - 1)] = p + (wv ? bwv : buv);
        }
    }
}

// ======================= v6 fallback (proven) =======================
#define NBLK 256
#define WS_MB 0
#define WS_HB (NBLK * 128 * 8)

__device__ __forceinline__ unsigned bulk_read_tag(const unsigned long long* s8,
                                                  float (*st)[516], int tid, unsigned ep)
{
    unsigned stab = 1u;
    #pragma unroll
    for (int r = 0; r < 2; ++r) {
        const int base = r * 4096 + tid;
        unsigned long long v[16];
        #pragma unroll
        for (int s = 0; s < 16; ++s)
            v[s] = __hip_atomic_load(&s8[base + s * 256], __ATOMIC_RELAXED, __HIP_MEMORY_SCOPE_AGENT);
        #pragma unroll
        for (int s = 0; s < 16; ++s) {
            int sp = 0;
            while ((((unsigned)(v[s] >> 32)) >> 1) != ep) {
                v[s] = __hip_atomic_load(&s8[base + s * 256], __ATOMIC_RELAXED, __HIP_MEMORY_SCOPE_AGENT);
                if (++sp > 4000000) break;
            }
            stab &= ((unsigned)(v[s] >> 32)) & 1u;
            const int u = base + s * 256;
            const int j = u & 127, ngp = u >> 7;
            st[j >> 3][ngp * 8 + (j & 7)] = __uint_as_float((unsigned)v[s]);
        }
    }
    return stab;
}

__device__ __forceinline__ void compute_gates(const float4 (&wr)[3][4], const float (*st)[516],
                                              int ks, float (&acc)[3][16])
{
    #pragma unroll
    for (int g = 0; g < 3; ++g)
        #pragma unroll
        for (int b = 0; b < 16; ++b) acc[g][b] = 0.f;
    #pragma unroll
    for (int j = 0; j < 4; ++j) {
        const int kw = 4 * (ks + 32 * j);
        #pragma unroll
        for (int b = 0; b < 16; ++b) {
            const float4 h4 = *(const float4*)&st[b][kw];
            #pragma unroll
            for (int g = 0; g < 3; ++g)
                acc[g][b] = fmaf(wr[g][j].x, h4.x, fmaf(wr[g][j].y, h4.y,
                            fmaf(wr[g][j].z, h4.z, fmaf(wr[g][j].w, h4.w, acc[g][b]))));
        }
    }
}

__device__ __forceinline__ void reduce_write(float (&acc)[3][16], float (*red)[8][49],
                                             int lane, int wv)
{
    #pragma unroll
    for (int g = 0; g < 3; ++g)
        #pragma unroll
        for (int b = 0; b < 16; ++b) {
            float v = acc[g][b];
            v += __shfl_xor(v, 8);
            v += __shfl_xor(v, 16);
            v += __shfl_xor(v, 32);
            acc[g][b] = v;
        }
    if ((lane & 56) == 0) {
        const int nn = lane & 7;
        #pragma unroll
        for (int g = 0; g < 3; ++g)
            #pragma unroll
            for (int b = 0; b < 16; ++b)
                red[wv][nn][g * 16 + b] = acc[g][b];
    }
    __syncthreads();
}

__global__ __launch_bounds__(NTHR, 1)
void fhn_v6(const float* __restrict__ u0, const float* __restrict__ w0,
            const float* __restrict__ Kp,
            const float* __restrict__ W_in, const float* __restrict__ b_in,
            const float* __restrict__ W0, const float* __restrict__ bi0, const float* __restrict__ bh0,
            const float* __restrict__ W1, const float* __restrict__ bi1, const float* __restrict__ bh1,
            const float* __restrict__ Wu, const float* __restrict__ bu,
            const float* __restrict__ Ww, const float* __restrict__ bw,
            float* __restrict__ out, unsigned char* __restrict__ wsb)
{
    __shared__ float staged[16][516];
    __shared__ float red[4][8][49];
    __shared__ float wu_s[H_], ww_s[H_];
    __shared__ float bias_s[48];
    __shared__ float s_uw4[4][32];
    __shared__ float s_uwF[32];
    __shared__ int s_w4[4];

    unsigned long long* mbU = (unsigned long long*)(wsb + WS_MB);
    unsigned long long* hbU = (unsigned long long*)(wsb + WS_HB);

    const int tid = threadIdx.x;
    const int bt = blockIdx.x & 3, ng = blockIdx.x >> 2;
    const int b0 = bt * 16;
    const int n = tid & 7, ks = tid >> 3;
    const int lane = tid & 63, wv = tid >> 6;
    const int fbase = bt * 64;
    const size_t sliceOff = (size_t)(fbase + ng) * 128;
    const unsigned long long* cohM = mbU + (size_t)fbase * 128;
    const unsigned long long* cohH = hbU + (size_t)fbase * 128;

    float4 w0r[3][4], w1r[3][4];
    {
        const int gmap[3] = {0, 2, 3};
        #pragma unroll
        for (int g = 0; g < 3; ++g) {
            const float* r0 = W0 + (size_t)(gmap[g] * H_ + ng * 8 + n) * H_;
            const float* r1 = W1 + (size_t)(gmap[g] * H_ + ng * 8 + n) * H_;
            #pragma unroll
            for (int j = 0; j < 4; ++j) {
                w0r[g][j] = *(const float4*)(r0 + 4 * (ks + 32 * j));
                w1r[g][j] = *(const float4*)(r1 + 4 * (ks + 32 * j));
            }
        }
    }
    for (int i = tid; i < H_; i += NTHR) { wu_s[i] = Wu[i]; ww_s[i] = Ww[i]; }
    if (tid < 48) {
        const int gmap[3] = {0, 2, 3};
        int L = tid / 24, r = tid % 24, g = r >> 3, nn = r & 7;
        int row = gmap[g] * H_ + ng * 8 + nn;
        bias_s[tid] = L ? (bi1[row] + bh1[row]) : (bi0[row] + bh0[row]);
    }
    const float buv = bu[0], bwv = bw[0];

    for (int i = tid; i < 16 * H_; i += NTHR) {
        int b = i >> 9, k = i & 511;
        staged[b][k] = u0[b0 + b] * W_in[k * 3] + w0[b0 + b] * W_in[k * 3 + 1]
                     + Kp[b0 + b] * W_in[k * 3 + 2] + b_in[k];
    }
    __syncthreads();

    float hprev = 0.f;
    int run = 0;
    float acc[3][16];

    for (int t = 0; t < T_; ++t) {
        if (t > 0) {
            unsigned myst = bulk_read_tag(cohH, staged, tid, 2u * (unsigned)t);
            int av = __all((int)myst);
            if (lane == 0) s_w4[wv] = av;
            __syncthreads();
            int stab = s_w4[0] & s_w4[1] & s_w4[2] & s_w4[3];
            run = stab ? run + 1 : 0;
            if (run >= RSTAB) {
                int b = tid & 15, uw = (tid >> 4) & 1, k8 = tid >> 5;
                const float* vec = uw ? ww_s : wu_s;
                float p = 0.f;
                #pragma unroll 8
                for (int i = 0; i < 64; ++i)
                    p = fmaf(vec[k8 * 64 + i], staged[b][k8 * 64 + i], p);
                p += __shfl_xor(p, 32);
                if ((tid & 32) == 0) s_uw4[wv][tid & 31] = p;
                __syncthreads();
                if (tid < 32)
                    s_uwF[tid] = s_uw4[0][tid] + s_uw4[1][tid] + s_uw4[2][tid] + s_uw4[3][tid]
                               + (tid >= 16 ? bwv : buv);
                __syncthreads();
                const int tau = t - 1;
                const int slot = tid & 31, b2 = slot & 15, uw2 = slot >> 4;
                const float val = s_uwF[slot];
                const size_t base = (uw2 ? (size_t)B_ * T_ : 0) + (size_t)(b0 + b2) * T_;
                for (int tp = tau + ng + 64 * (tid >> 5); tp < T_; tp += 512)
                    out[base + tp] = val;
                return;
            }
        }

        compute_gates(w0r, staged, ks, acc);
        reduce_write(acc, red, lane, wv);
        if (tid < 128) {
            int b = tid >> 3, nn = tid & 7;
            float si = red[0][nn][b]      + red[1][nn][b]      + red[2][nn][b]      + red[3][nn][b]      + bias_s[nn];
            float sg = red[0][nn][16 + b] + red[1][nn][16 + b] + red[2][nn][16 + b] + red[3][nn][16 + b] + bias_s[8 + nn];
            float so = red[0][nn][32 + b] + red[1][nn][32 + b] + red[2][nn][32 + b] + red[3][nn][32 + b] + bias_s[16 + nn];
            float c = sigf(si) * tanhf(sg);
            float m = sigf(so) * tanhf(c);
            unsigned long long pkt = ((unsigned long long)((((2u * t + 1u) << 1) | 1u)) << 32)
                                   | (unsigned long long)__float_as_uint(m);
            __hip_atomic_store(&mbU[sliceOff + tid], pkt, __ATOMIC_RELAXED, __HIP_MEMORY_SCOPE_AGENT);
        }
        if (t > 0 && ng < 4) {
            const int bb = (ng << 2) + wv;
            const float4* h4p = (const float4*)&staged[bb][lane << 3];
            const float4* u4p = (const float4*)&wu_s[lane << 3];
            const float4* w4p = (const float4*)&ww_s[lane << 3];
            const float4 h0v = h4p[0], h1v = h4p[1];
            const float4 ua = u4p[0], ub = u4p[1];
            const float4 wa = w4p[0], wb = w4p[1];
            float pu = 0.f, pw = 0.f;
            CH8(pu, ua, ub, h0v, h1v);
            CH8(pw, wa, wb, h0v, h1v);
            #pragma unroll
            for (int off = 1; off < 64; off <<= 1) {
                pu += __shfl_xor(pu, off);
                pw += __shfl_xor(pw, off);
            }
            if (lane == 0) {
                out[(size_t)(b0 + bb) * T_ + (t - 1)] = pu + buv;
                out[(size_t)B_ * T_ + (size_t)(b0 + bb) * T_ + (t - 1)] = pw + bwv;
            }
        }

        bulk_read_tag(cohM, staged, tid, 2u * t + 1u);
        __syncthreads();

        compute_gates(w1r, staged, ks, acc);
        reduce_write(acc, red, lane, wv);
        float hval = 0.f; int myst2 = 1;
        if (tid < 128) {
            int b = tid >> 3, nn = tid & 7;
            float si = red[0][nn][b]      + red[1][nn][b]      + red[2][nn][b]      + red[3][nn][b]      + bias_s[24 + nn];
            float sg = red[0][nn][16 + b] + red[1][nn][16 + b] + red[2][nn][16 + b] + red[3][nn][16 + b] + bias_s[32 + nn];
            float so = red[0][nn][32 + b] + red[1][nn][32 + b] + red[2][nn][32 + b] + red[3][nn][32 + b] + bias_s[40 + nn];
            float c = sigf(si) * tanhf(sg);
            hval = sigf(so) * tanhf(c);
            myst2 = (fabsf(hval - hprev) < EPS_STAB) ? 1 : 0;
            hprev = hval;
        }
        {
            int av = __all(myst2);
            if (lane == 0) s_w4[wv] = av;
            __syncthreads();
            unsigned sb = (t == 0) ? 0u : (unsigned)(s_w4[0] & s_w4[1] & s_w4[2] & s_w4[3]);
            if (tid < 128) {
                unsigned long long pkt = ((unsigned long long)((((2u * t + 2u) << 1) | sb)) << 32)
                                       | (unsigned long long)__float_as_uint(hval);
                __hip_atomic_store(&hbU[sliceOff + tid], pkt, __ATOMIC_RELAXED, __HIP_MEMORY_SCOPE_AGENT);
            }
        }
    }

    if (ng < 4) {
        bulk_read_tag(cohH, staged, tid, 2u * (unsigned)T_);
        __syncthreads();
        const int bb = (ng << 2) + wv;
        const float4* h4p = (const float4*)&staged[bb][lane << 3];
        const float4* u4p = (const float4*)&wu_s[lane << 3];
        const float4* w4p = (const float4*)&ww_s[lane << 3];
        const float4 h0v = h4p[0], h1v = h4p[1];
        const float4 ua = u4p[0], ub = u4p[1];
        const float4 wa = w4p[0], wb = w4p[1];
        float pu = 0.f, pw = 0.f;
        CH8(pu, ua, ub, h0v, h1v);
        CH8(pw, wa, wb, h0v, h1v);
        #pragma unroll
        for (int off = 1; off < 64; off <<= 1) {
            pu += __shfl_xor(pu, off);
            pw += __shfl_xor(pw, off);
        }
        if (lane == 0) {
            out[(size_t)(b0 + bb) * T_ + (T_ - 1)] = pu + buv;
            out[(size_t)B_ * T_ + (size_t)(b0 + bb) * T_ + (T_ - 1)] = pw + bwv;
        }
    }
}

extern "C" void kernel_launch(void* const* d_in, const int* in_sizes, int n_in,
                              void* d_out, int out_size, void* d_ws, size_t ws_size,
                              hipStream_t stream) {
    const float* u0   = (const float*)d_in[0];
    const float* w0   = (const float*)d_in[1];
    const float* K    = (const float*)d_in[2];
    const float* W_in = (const float*)d_in[3];
    const float* b_in = (const float*)d_in[4];
    const float* W0   = (const float*)d_in[5];   // W_ih0 (W_hh0=d_in[6] dead)
    const float* bi0  = (const float*)d_in[7];
    const float* bh0  = (const float*)d_in[8];
    const float* W1   = (const float*)d_in[9];   // W_ih1 (W_hh1=d_in[10] dead)
    const float* bi1  = (const float*)d_in[11];
    const float* bh1  = (const float*)d_in[12];
    const float* Wu   = (const float*)d_in[13];
    const float* bu   = (const float*)d_in[14];
    const float* Ww   = (const float*)d_in[15];
    const float* bw   = (const float*)d_in[16];

    if (ws_size >= (size_t)W7_NEED) {
        hipMemsetAsync(d_ws, 0, 4096, stream);   // roster counters
        fhn_v7<<<dim3(2048), dim3(NTHR), 0, stream>>>(
            u0, w0, K, W_in, b_in, W0, bi0, bh0, W1, bi1, bh1, Wu, bu, Ww, bw,
            (float*)d_out, (unsigned char*)d_ws);
    } else {
        // proven v6 path (tags reject poison; no memset needed)
        fhn_v6<<<dim3(NBLK), dim3(NTHR), 0, stream>>>(
            u0, w0, K, W_in, b_in, W0, bi0, bh0, W1, bi1, bh1, Wu, bu, Ww, bw,
            (float*)d_out, (unsigned char*)d_ws);
    }
}